// Round 20
// baseline (41.313 us; speedup 1.0000x reference)
//
#include <hip/hip_runtime.h>

#define INP (128*128*64)   // 1048576
#define NB 8
#define NBLK8 512          // k_sample blocks per batch: (INP/8)/256

typedef __attribute__((ext_vector_type(4))) float f32x4;
typedef __attribute__((ext_vector_type(2))) float f32x2;
typedef int v4i __attribute__((ext_vector_type(4)));

#if __has_builtin(__builtin_amdgcn_make_buffer_rsrc) && __has_builtin(__builtin_amdgcn_raw_buffer_load_b32)
#define RSRC_T __amdgpu_buffer_rsrc_t
__device__ __forceinline__ RSRC_T make_rsrc(const float* p) {
    return __builtin_amdgcn_make_buffer_rsrc((void*)p, (short)0, INP * 4, 0x00020000);
}
__device__ __forceinline__ float bload(RSRC_T r, int boff) {
    return __builtin_bit_cast(float, __builtin_amdgcn_raw_buffer_load_b32(r, boff, 0, 0));
}
#else
#define RSRC_T v4i
__device__ __forceinline__ RSRC_T make_rsrc(const float* p) {
    union { const float* p; unsigned u[2]; } pun; pun.p = p;
    RSRC_T r;
    r.x = (int)pun.u[0]; r.y = (int)pun.u[1]; r.z = INP * 4; r.w = 0x00020000;
    return r;
}
__device__ __forceinline__ float bload(RSRC_T r, int boff) {
    return __builtin_amdgcn_raw_buffer_load_f32(r, boff, 0, 0);
}
#endif

#if __has_builtin(__builtin_amdgcn_raw_buffer_load_b64)
__device__ __forceinline__ f32x2 bload2(RSRC_T r, int boff) {
    return __builtin_bit_cast(f32x2, __builtin_amdgcn_raw_buffer_load_b64(r, boff, 0, 0));
}
#else
__device__ __forceinline__ f32x2 bload2(RSRC_T r, int boff) {
    f32x2 v; v.x = bload(r, boff); v.y = bload(r, boff + 4); return v;
}
#endif

__device__ __forceinline__ float wave_reduce(float v) {
    #pragma unroll
    for (int off = 32; off > 0; off >>= 1) v += __shfl_down(v, off, 64);
    return v;
}

// R13-proven per-voxel prep: clamped always-in-bounds offsets + x-edges
// resolved in the weights. (R3/R7: never pair a possibly-negative SRSRC
// voffset with a folded imm.)
struct Prep {
    int o[4];
    float wa, wb, wy0, wy1, wz0, wz1;
};

__device__ __forceinline__ Prep prep_s(float ix, float iy, float iz) {
    const float fx = floorf(ix), fy = floorf(iy), fz = floorf(iz);
    const int x0 = (int)fx, y0 = (int)fy, z0 = (int)fz;
    const int x1 = x0 + 1,  y1 = y0 + 1,  z1 = z0 + 1;

    const float wx1 = ix - fx, wx0 = 1.f - wx1;
    Prep p;
    p.wy1 = iy - fy; p.wy0 = 1.f - p.wy1;
    p.wz1 = iz - fz; p.wz0 = 1.f - p.wz1;
    p.wy0 = ((unsigned)y0 < 128u) ? p.wy0 : 0.f;
    p.wy1 = ((unsigned)y1 < 128u) ? p.wy1 : 0.f;
    p.wz0 = ((unsigned)z0 < 128u) ? p.wz0 : 0.f;
    p.wz1 = ((unsigned)z1 < 128u) ? p.wz1 : 0.f;

    const float wx0z = ((unsigned)x0 < 64u) ? wx0 : 0.f;
    const float wx1z = ((unsigned)x1 < 64u) ? wx1 : 0.f;
    const bool hi = (x0 >= 63);
    const bool lo = (x0 < 0);
    p.wa = lo ? wx1z : (hi ? 0.f : wx0z);
    p.wb = hi ? wx0z : (lo ? 0.f : wx1z);

    const int yc0 = min(max(y0, 0), 127), yc1 = min(max(y1, 0), 127);
    const int zc0 = min(max(z0, 0), 127), zc1 = min(max(z1, 0), 127);
    const int xpb = min(max(x0, 0), 62) << 2;
    const int yb0 = (yc0 << 8) + xpb, yb1 = (yc1 << 8) + xpb;
    const int zb0 = zc0 << 15,        zb1 = zc1 << 15;
    p.o[0] = zb0 + yb0; p.o[1] = zb0 + yb1;
    p.o[2] = zb1 + yb0; p.o[3] = zb1 + yb1;
    return p;
}

__device__ __forceinline__ float blend_s(const Prep& p, const f32x2 v[4]) {
    const float bx00 = fmaf(p.wb, v[0].y, p.wa * v[0].x);
    const float bx01 = fmaf(p.wb, v[1].y, p.wa * v[1].x);
    const float bx10 = fmaf(p.wb, v[2].y, p.wa * v[2].x);
    const float bx11 = fmaf(p.wb, v[3].y, p.wa * v[3].x);
    const float by0  = fmaf(p.wy1, bx01, p.wy0 * bx00);
    const float by1  = fmaf(p.wy1, bx11, p.wy0 * bx10);
    return fmaf(p.wz1, by1, p.wz0 * by0);
}

// ---------------------------------------------------------------------------
// K1: one thread = EIGHT x-consecutive voxels (a wave covers 8 full x-rows;
// per-voxel line footprint unchanged vs R13/R19). R19-proven recipe scaled
// up: single matvec + delta coords (d/dw = t0, 2*t4, 2*t8), all 8 preps
// (named, no runtime-indexed arrays -> no scratch), all 32 dwordx2 gathers
// issued, then 8 blends. Two f32x4 NT stores + 2 f32x4 lnw loads + one tail.
// ---------------------------------------------------------------------------
__global__ __launch_bounds__(256) void k_sample(
    const float* __restrict__ x, const int* __restrict__ r_index,
    const float* __restrict__ theta, const float* __restrict__ lnw,
    float* __restrict__ x_reg, float* __restrict__ partial)
{
    const int b  = blockIdx.y;
    const int i8 = blockIdx.x * 256 + threadIdx.x;   // oct index
    const int w0 = (i8 & 7) << 3;                    // w of voxel 0
    const int h  = (i8 >> 3) & 127;
    const int d  = i8 >> 10;

    const f32x4 wA = ((const f32x4*)lnw)[i8 * 2];     // issue early
    const f32x4 wB = ((const f32x4*)lnw)[i8 * 2 + 1];

    const float xs = fmaf((float)w0, 1.f/32.f, 1.f/64.f  - 1.f);
    const float ys = fmaf((float)h,  1.f/64.f, 1.f/128.f - 1.f);
    const float zs = fmaf((float)d,  1.f/64.f, 1.f/128.f - 1.f);

    const float* __restrict__ t = theta + r_index[b] * 12;   // uniform
    const float gx = fmaf(t[0], xs, fmaf(t[1], ys, fmaf(t[2],  zs, t[3])));
    const float gy = fmaf(t[4], xs, fmaf(t[5], ys, fmaf(t[6],  zs, t[7])));
    const float gz = fmaf(t[8], xs, fmaf(t[9], ys, fmaf(t[10], zs, t[11])));
    const float ix0 = fmaf(gx, 32.f, 31.5f);
    const float iy0 = fmaf(gy, 64.f, 63.5f);
    const float iz0 = fmaf(gz, 64.f, 63.5f);
    const float sx = t[0], sy = 2.f * t[4], sz = 2.f * t[8];

    // all 8 preps (independent VALU chains; named, rule #20)
    const Prep p0 = prep_s(ix0, iy0, iz0);
    const Prep p1 = prep_s(ix0 + sx, iy0 + sy, iz0 + sz);
    const Prep p2 = prep_s(fmaf(2.f, sx, ix0), fmaf(2.f, sy, iy0), fmaf(2.f, sz, iz0));
    const Prep p3 = prep_s(fmaf(3.f, sx, ix0), fmaf(3.f, sy, iy0), fmaf(3.f, sz, iz0));
    const Prep p4 = prep_s(fmaf(4.f, sx, ix0), fmaf(4.f, sy, iy0), fmaf(4.f, sz, iz0));
    const Prep p5 = prep_s(fmaf(5.f, sx, ix0), fmaf(5.f, sy, iy0), fmaf(5.f, sz, iz0));
    const Prep p6 = prep_s(fmaf(6.f, sx, ix0), fmaf(6.f, sy, iy0), fmaf(6.f, sz, iz0));
    const Prep p7 = prep_s(fmaf(7.f, sx, ix0), fmaf(7.f, sy, iy0), fmaf(7.f, sz, iz0));

    // all 32 gathers issued before any blend
    const RSRC_T r = make_rsrc(x + (size_t)b * INP);
    f32x2 v0[4], v1[4], v2[4], v3[4], v4[4], v5[4], v6[4], v7[4];
    #pragma unroll
    for (int j = 0; j < 4; ++j) v0[j] = bload2(r, p0.o[j]);
    #pragma unroll
    for (int j = 0; j < 4; ++j) v1[j] = bload2(r, p1.o[j]);
    #pragma unroll
    for (int j = 0; j < 4; ++j) v2[j] = bload2(r, p2.o[j]);
    #pragma unroll
    for (int j = 0; j < 4; ++j) v3[j] = bload2(r, p3.o[j]);
    #pragma unroll
    for (int j = 0; j < 4; ++j) v4[j] = bload2(r, p4.o[j]);
    #pragma unroll
    for (int j = 0; j < 4; ++j) v5[j] = bload2(r, p5.o[j]);
    #pragma unroll
    for (int j = 0; j < 4; ++j) v6[j] = bload2(r, p6.o[j]);
    #pragma unroll
    for (int j = 0; j < 4; ++j) v7[j] = bload2(r, p7.o[j]);

    const float o0 = blend_s(p0, v0);
    const float o1 = blend_s(p1, v1);
    const float o2 = blend_s(p2, v2);
    const float o3 = blend_s(p3, v3);
    const float o4 = blend_s(p4, v4);
    const float o5 = blend_s(p5, v5);
    const float o6 = blend_s(p6, v6);
    const float o7 = blend_s(p7, v7);

    f32x4 oA; oA.x = o0; oA.y = o1; oA.z = o2; oA.w = o3;
    f32x4 oB; oB.x = o4; oB.y = o5; oB.z = o6; oB.w = o7;
    f32x4* dst = (f32x4*)(x_reg + (size_t)b * INP) + i8 * 2;
    __builtin_nontemporal_store(oA, dst);
    __builtin_nontemporal_store(oB, dst + 1);

    // R5-proven tail: wave shfl reduce -> LDS combine -> ONE store per block
    float acc = fmaf(o0, wA.x, o1 * wA.y) + fmaf(o2, wA.z, o3 * wA.w)
              + fmaf(o4, wB.x, o5 * wB.y) + fmaf(o6, wB.z, o7 * wB.w);
    acc = wave_reduce(acc);
    __shared__ float sm[4];
    if ((threadIdx.x & 63) == 0) sm[threadIdx.x >> 6] = acc;
    __syncthreads();
    if (threadIdx.x == 0)
        partial[b * NBLK8 + blockIdx.x] = sm[0] + sm[1] + sm[2] + sm[3];
}

// ---------------------------------------------------------------------------
// K2 (fused reduce+outer, R13-proven): grid (128 chunks, 8 batches). Each
// block redundantly reduces its batch's 512 partials (1 f32x2/thread) then
// writes its 8192-float chunk of L[b] = s_b * lnw.
// ---------------------------------------------------------------------------
__global__ __launch_bounds__(256) void k_outer(
    const float* __restrict__ lnw, const float* __restrict__ partial,
    float* __restrict__ L)
{
    const int b   = blockIdx.y;
    const int tid = threadIdx.x;

    const f32x2* p2 = (const f32x2*)(partial + b * NBLK8);   // 256 f32x2
    const f32x2 a0 = p2[tid];
    float v = a0.x + a0.y;
    v = wave_reduce(v);
    __shared__ float sm[4];
    __shared__ float smt;
    if ((tid & 63) == 0) sm[tid >> 6] = v;
    __syncthreads();
    if (tid == 0) smt = (sm[0] + sm[1]) + (sm[2] + sm[3]);
    __syncthreads();
    const float sb = smt;

    const int base = blockIdx.x * 2048 + tid;    // f32x4 units within batch
    const f32x4* w4p = (const f32x4*)lnw;
    f32x4* L4 = (f32x4*)L + (size_t)b * (INP / 4);
    #pragma unroll
    for (int k = 0; k < 8; ++k) {
        const f32x4 w4 = w4p[base + k * 256];
        __builtin_nontemporal_store(sb * w4, L4 + base + k * 256);
    }
}

extern "C" void kernel_launch(void* const* d_in, const int* in_sizes, int n_in,
                              void* d_out, int out_size, void* d_ws, size_t ws_size,
                              hipStream_t stream) {
    const float* x       = (const float*)d_in[0];
    const int*   r_index = (const int*)d_in[1];
    const float* theta   = (const float*)d_in[2];
    const float* lnw     = (const float*)d_in[3];

    float* x_reg = (float*)d_out;
    float* L     = (float*)d_out + (size_t)NB * INP;

    float* partial = (float*)d_ws;            // 8*512 floats = 16 KB

    dim3 grid1(NBLK8, NB);
    k_sample<<<grid1, 256, 0, stream>>>(x, r_index, theta, lnw, x_reg, partial);
    dim3 grid2(128, NB);
    k_outer<<<grid2, 256, 0, stream>>>(lnw, partial, L);
}

// Round 21
// 32.746 us; speedup vs baseline: 1.2616x; 1.2616x over previous
//
#include <hip/hip_runtime.h>

#define INP (128*128*64)   // 1048576
#define NB 8
#define NBLK4 1024         // k_sample blocks per batch: (INP/4)/256

typedef __attribute__((ext_vector_type(4))) float f32x4;
typedef __attribute__((ext_vector_type(2))) float f32x2;
typedef int v4i __attribute__((ext_vector_type(4)));

#if __has_builtin(__builtin_amdgcn_make_buffer_rsrc) && __has_builtin(__builtin_amdgcn_raw_buffer_load_b32)
#define RSRC_T __amdgpu_buffer_rsrc_t
__device__ __forceinline__ RSRC_T make_rsrc(const float* p) {
    return __builtin_amdgcn_make_buffer_rsrc((void*)p, (short)0, INP * 4, 0x00020000);
}
__device__ __forceinline__ float bload(RSRC_T r, int boff) {
    return __builtin_bit_cast(float, __builtin_amdgcn_raw_buffer_load_b32(r, boff, 0, 0));
}
#else
#define RSRC_T v4i
__device__ __forceinline__ RSRC_T make_rsrc(const float* p) {
    union { const float* p; unsigned u[2]; } pun; pun.p = p;
    RSRC_T r;
    r.x = (int)pun.u[0]; r.y = (int)pun.u[1]; r.z = INP * 4; r.w = 0x00020000;
    return r;
}
__device__ __forceinline__ float bload(RSRC_T r, int boff) {
    return __builtin_amdgcn_raw_buffer_load_f32(r, boff, 0, 0);
}
#endif

#if __has_builtin(__builtin_amdgcn_raw_buffer_load_b64)
__device__ __forceinline__ f32x2 bload2(RSRC_T r, int boff) {
    return __builtin_bit_cast(f32x2, __builtin_amdgcn_raw_buffer_load_b64(r, boff, 0, 0));
}
#else
__device__ __forceinline__ f32x2 bload2(RSRC_T r, int boff) {
    f32x2 v; v.x = bload(r, boff); v.y = bload(r, boff + 4); return v;
}
#endif

__device__ __forceinline__ float wave_reduce(float v) {
    #pragma unroll
    for (int off = 32; off > 0; off >>= 1) v += __shfl_down(v, off, 64);
    return v;
}

// R13-proven per-voxel prep: clamped always-in-bounds offsets + x-edges
// resolved in the weights. (R3/R7: never pair a possibly-negative SRSRC
// voffset with a folded imm.)
struct Prep {
    int o[4];
    float wa, wb, wy0, wy1, wz0, wz1;
};

__device__ __forceinline__ Prep prep_s(float ix, float iy, float iz) {
    const float fx = floorf(ix), fy = floorf(iy), fz = floorf(iz);
    const int x0 = (int)fx, y0 = (int)fy, z0 = (int)fz;
    const int x1 = x0 + 1,  y1 = y0 + 1,  z1 = z0 + 1;

    const float wx1 = ix - fx, wx0 = 1.f - wx1;
    Prep p;
    p.wy1 = iy - fy; p.wy0 = 1.f - p.wy1;
    p.wz1 = iz - fz; p.wz0 = 1.f - p.wz1;
    p.wy0 = ((unsigned)y0 < 128u) ? p.wy0 : 0.f;
    p.wy1 = ((unsigned)y1 < 128u) ? p.wy1 : 0.f;
    p.wz0 = ((unsigned)z0 < 128u) ? p.wz0 : 0.f;
    p.wz1 = ((unsigned)z1 < 128u) ? p.wz1 : 0.f;

    const float wx0z = ((unsigned)x0 < 64u) ? wx0 : 0.f;
    const float wx1z = ((unsigned)x1 < 64u) ? wx1 : 0.f;
    const bool hi = (x0 >= 63);
    const bool lo = (x0 < 0);
    p.wa = lo ? wx1z : (hi ? 0.f : wx0z);
    p.wb = hi ? wx0z : (lo ? 0.f : wx1z);

    const int yc0 = min(max(y0, 0), 127), yc1 = min(max(y1, 0), 127);
    const int zc0 = min(max(z0, 0), 127), zc1 = min(max(z1, 0), 127);
    const int xpb = min(max(x0, 0), 62) << 2;
    const int yb0 = (yc0 << 8) + xpb, yb1 = (yc1 << 8) + xpb;
    const int zb0 = zc0 << 15,        zb1 = zc1 << 15;
    p.o[0] = zb0 + yb0; p.o[1] = zb0 + yb1;
    p.o[2] = zb1 + yb0; p.o[3] = zb1 + yb1;
    return p;
}

__device__ __forceinline__ float blend_s(const Prep& p, const f32x2 v[4]) {
    const float bx00 = fmaf(p.wb, v[0].y, p.wa * v[0].x);
    const float bx01 = fmaf(p.wb, v[1].y, p.wa * v[1].x);
    const float bx10 = fmaf(p.wb, v[2].y, p.wa * v[2].x);
    const float bx11 = fmaf(p.wb, v[3].y, p.wa * v[3].x);
    const float by0  = fmaf(p.wy1, bx01, p.wy0 * bx00);
    const float by1  = fmaf(p.wy1, bx11, p.wy0 * bx10);
    return fmaf(p.wz1, by1, p.wz0 * by0);
}

// ---------------------------------------------------------------------------
// K1 (R19, session best — 8x/thread in R20 inverted: VGPR ceiling
// re-serialized loads and doubled HBM fetch): one thread = FOUR
// x-consecutive voxels; single matvec + delta coords (d/dw = t0, 2*t4,
// 2*t8); all 4 preps, then all 16 dwordx2 gathers, then 4 blends; one
// f32x4 NT store + f32x4 lnw load + one tail per 4 voxels.
// ---------------------------------------------------------------------------
__global__ __launch_bounds__(256) void k_sample(
    const float* __restrict__ x, const int* __restrict__ r_index,
    const float* __restrict__ theta, const float* __restrict__ lnw,
    float* __restrict__ x_reg, float* __restrict__ partial)
{
    const int b  = blockIdx.y;
    const int i4 = blockIdx.x * 256 + threadIdx.x;   // quad index
    const int w0 = (i4 & 15) << 2;                   // w of voxel 0
    const int h  = (i4 >> 4) & 127;
    const int d  = i4 >> 11;

    const f32x4 w4 = ((const f32x4*)lnw)[i4];        // issue early

    const float xs = fmaf((float)w0, 1.f/32.f, 1.f/64.f  - 1.f);
    const float ys = fmaf((float)h,  1.f/64.f, 1.f/128.f - 1.f);
    const float zs = fmaf((float)d,  1.f/64.f, 1.f/128.f - 1.f);

    const float* __restrict__ t = theta + r_index[b] * 12;   // uniform
    const float gx = fmaf(t[0], xs, fmaf(t[1], ys, fmaf(t[2],  zs, t[3])));
    const float gy = fmaf(t[4], xs, fmaf(t[5], ys, fmaf(t[6],  zs, t[7])));
    const float gz = fmaf(t[8], xs, fmaf(t[9], ys, fmaf(t[10], zs, t[11])));
    const float ix0 = fmaf(gx, 32.f, 31.5f);
    const float iy0 = fmaf(gy, 64.f, 63.5f);
    const float iz0 = fmaf(gz, 64.f, 63.5f);
    const float sx = t[0], sy = 2.f * t[4], sz = 2.f * t[8];

    // all 4 preps first (independent VALU chains)
    const Prep p0 = prep_s(ix0, iy0, iz0);
    const Prep p1 = prep_s(ix0 + sx, iy0 + sy, iz0 + sz);
    const Prep p2 = prep_s(fmaf(2.f, sx, ix0), fmaf(2.f, sy, iy0), fmaf(2.f, sz, iz0));
    const Prep p3 = prep_s(fmaf(3.f, sx, ix0), fmaf(3.f, sy, iy0), fmaf(3.f, sz, iz0));

    // all 16 gathers issued before any blend
    const RSRC_T r = make_rsrc(x + (size_t)b * INP);
    f32x2 v0[4], v1[4], v2[4], v3[4];
    #pragma unroll
    for (int j = 0; j < 4; ++j) v0[j] = bload2(r, p0.o[j]);
    #pragma unroll
    for (int j = 0; j < 4; ++j) v1[j] = bload2(r, p1.o[j]);
    #pragma unroll
    for (int j = 0; j < 4; ++j) v2[j] = bload2(r, p2.o[j]);
    #pragma unroll
    for (int j = 0; j < 4; ++j) v3[j] = bload2(r, p3.o[j]);

    const float o0 = blend_s(p0, v0);
    const float o1 = blend_s(p1, v1);
    const float o2 = blend_s(p2, v2);
    const float o3 = blend_s(p3, v3);

    f32x4 o; o.x = o0; o.y = o1; o.z = o2; o.w = o3;
    __builtin_nontemporal_store(o, (f32x4*)(x_reg + (size_t)b * INP) + i4);

    // R5-proven tail: wave shfl reduce -> LDS combine -> ONE store per block
    float acc = fmaf(o0, w4.x, o1 * w4.y) + fmaf(o2, w4.z, o3 * w4.w);
    acc = wave_reduce(acc);
    __shared__ float sm[4];
    if ((threadIdx.x & 63) == 0) sm[threadIdx.x >> 6] = acc;
    __syncthreads();
    if (threadIdx.x == 0)
        partial[b * NBLK4 + blockIdx.x] = sm[0] + sm[1] + sm[2] + sm[3];
}

// ---------------------------------------------------------------------------
// K2 (fused reduce+outer, R13-proven): grid (128 chunks, 8 batches). Each
// block redundantly reduces its batch's 1024 partials (1 f32x4/thread) then
// writes its 8192-float chunk of L[b] = s_b * lnw.
// ---------------------------------------------------------------------------
__global__ __launch_bounds__(256) void k_outer(
    const float* __restrict__ lnw, const float* __restrict__ partial,
    float* __restrict__ L)
{
    const int b   = blockIdx.y;
    const int tid = threadIdx.x;

    const f32x4* p4 = (const f32x4*)(partial + b * NBLK4);   // 256 f32x4
    const f32x4 a0 = p4[tid];
    float v = (a0.x + a0.y) + (a0.z + a0.w);
    v = wave_reduce(v);
    __shared__ float sm[4];
    __shared__ float smt;
    if ((tid & 63) == 0) sm[tid >> 6] = v;
    __syncthreads();
    if (tid == 0) smt = (sm[0] + sm[1]) + (sm[2] + sm[3]);
    __syncthreads();
    const float sb = smt;

    const int base = blockIdx.x * 2048 + tid;    // f32x4 units within batch
    const f32x4* w4p = (const f32x4*)lnw;
    f32x4* L4 = (f32x4*)L + (size_t)b * (INP / 4);
    #pragma unroll
    for (int k = 0; k < 8; ++k) {
        const f32x4 w4 = w4p[base + k * 256];
        __builtin_nontemporal_store(sb * w4, L4 + base + k * 256);
    }
}

extern "C" void kernel_launch(void* const* d_in, const int* in_sizes, int n_in,
                              void* d_out, int out_size, void* d_ws, size_t ws_size,
                              hipStream_t stream) {
    const float* x       = (const float*)d_in[0];
    const int*   r_index = (const int*)d_in[1];
    const float* theta   = (const float*)d_in[2];
    const float* lnw     = (const float*)d_in[3];

    float* x_reg = (float*)d_out;
    float* L     = (float*)d_out + (size_t)NB * INP;

    float* partial = (float*)d_ws;            // 8*1024 floats = 32 KB

    dim3 grid1(NBLK4, NB);
    k_sample<<<grid1, 256, 0, stream>>>(x, r_index, theta, lnw, x_reg, partial);
    dim3 grid2(128, NB);
    k_outer<<<grid2, 256, 0, stream>>>(lnw, partial, L);
}